// Round 9
// baseline (38.920 us; speedup 1.0000x reference)
//
#include <hip/hip_runtime.h>
#include <hip/hip_bf16.h>

#define NND 2000
#define KNB 16
#define CS 128
#define CZ 64
#define NE (NND*KNB)

typedef __attribute__((ext_vector_type(8))) short short8;
typedef __attribute__((ext_vector_type(4))) float f32x4;
typedef __attribute__((ext_vector_type(4))) unsigned int uint4v;

// hardware bf16 convert (compiler emits v_cvt_pk_bf16_f32; RNE)
__device__ __forceinline__ unsigned int pk2(float a, float b) {
  __hip_bfloat162 h = __float22bfloat162_rn(make_float2(a, b));
  unsigned int u;
  __builtin_memcpy(&u, &h, 4);
  return u;
}
__device__ __forceinline__ unsigned short bfc(float f) {
  __hip_bfloat16 h = __float2bfloat16(f);
  unsigned short u;
  __builtin_memcpy(&u, &h, 2);
  return u;
}

__device__ __forceinline__ float fexp2(float x) {
#if __has_builtin(__builtin_amdgcn_exp2f)
  return __builtin_amdgcn_exp2f(x);
#else
  return __expf(0.6931471805599453f * x);
#endif
}

// ---------------------------------------------------------------------------
// Precompute (r5 form):
//   blocks [0,500): per-node gate logits G1/G2 (ILP-4), b_gate folded in G1,
//                   log2e folded into both (gate uses exp2).
//   block 500: wave0 bias2; wave1 wdbF; wave2 wedF; wave3 woF (bf16 frags).
// ---------------------------------------------------------------------------
__global__ __launch_bounds__(256) void precompute_kernel(
    const float* __restrict__ nf,
    const float* __restrict__ w_gate, const float* __restrict__ b_gate,
    const float* __restrict__ ln_b, const float* __restrict__ w_out,
    const float* __restrict__ b_out,
    const float* __restrict__ w_db, const float* __restrict__ w_edge,
    const float* __restrict__ ln_g,
    float* __restrict__ g1, float* __restrict__ g2, float* __restrict__ bias2,
    unsigned short* __restrict__ wdbF, unsigned short* __restrict__ wedF,
    unsigned short* __restrict__ woF)
{
  const int p = threadIdx.x;
  const int lane = p & 63;
  const int wv   = p >> 6;
  const int b    = blockIdx.x;
  if (b < NND/4) {
    const int v = b*4 + wv;
    const float* nrow = nf + v*CS;
    float a10=0.f,a11=0.f,a12=0.f,a13=0.f;
    float a20=0.f,a21=0.f,a22=0.f,a23=0.f;
    #pragma unroll
    for (int cc = 0; cc < CS; cc += 4) {
      const f32x4 x = *(const f32x4*)&nrow[cc];
      a10 = fmaf(x[0], w_gate[(cc+0)*CZ + lane], a10);
      a11 = fmaf(x[1], w_gate[(cc+1)*CZ + lane], a11);
      a12 = fmaf(x[2], w_gate[(cc+2)*CZ + lane], a12);
      a13 = fmaf(x[3], w_gate[(cc+3)*CZ + lane], a13);
      a20 = fmaf(x[0], w_gate[(CS+cc+0)*CZ + lane], a20);
      a21 = fmaf(x[1], w_gate[(CS+cc+1)*CZ + lane], a21);
      a22 = fmaf(x[2], w_gate[(CS+cc+2)*CZ + lane], a22);
      a23 = fmaf(x[3], w_gate[(CS+cc+3)*CZ + lane], a23);
    }
    const float a1 = b_gate[lane] + ((a10+a11)+(a12+a13));
    const float a2 = (a20+a21)+(a22+a23);
    g1[v*CZ + lane] = a1 * 1.4426950408889634f;
    g2[v*CZ + lane] = a2 * 1.4426950408889634f;
  } else {
    if (wv == 0) {
      float a = b_out[lane];
      #pragma unroll
      for (int cc = 0; cc < CZ; ++cc)
        a = fmaf(ln_b[cc], w_out[cc*CZ + lane], a);
      bias2[lane] = a;
    } else if (wv == 1) {
      for (int e = lane; e < 4096; e += 64) {
        const int entry = e >> 3, t = e & 7;
        const int l2 = entry & 63, sn = entry >> 6;
        const int s = sn >> 2, nt = sn & 3;
        const int q2 = l2 >> 4, c2 = l2 & 15;
        wdbF[e] = bfc(w_db[(32*s + 8*q2 + t)*CZ + 16*nt + c2]);
      }
    } else if (wv == 2) {
      for (int e = lane; e < 4096; e += 64) {
        const int entry = e >> 3, t = e & 7;
        const int p2 = entry & 255, s = entry >> 8;
        const int q2 = (p2 >> 4) & 3, c2 = p2 & 15;
        wedF[e] = bfc(w_edge[(32*s + 8*q2 + t)*CZ + 16*(p2 >> 6) + c2]);
      }
    } else {
      for (int e = lane; e < 4096; e += 64) {
        const int entry = e >> 3, t = e & 7;
        const int p2 = entry & 255, s = entry >> 8;
        const int q2 = (p2 >> 4) & 3, c2 = p2 & 15;
        const int k = 32*s + 8*q2 + t;
        woF[e] = bfc(w_out[k*CZ + 16*(p2 >> 6) + c2] * ln_g[k]);
      }
    }
  }
}

// ---------------------------------------------------------------------------
// Fused main kernel: ONE WAVE per node (64-thread blocks), ZERO barriers.
//   kf held in registers (MFMA0 C-frag == gate-phase layout), G1 rows in
//   registers, G2/t_j/xh via wave-private LDS (lgkmcnt-ordered, no syncs).
//   mt loop streams the 16 j-tiles: dist -> rbf A-frag -> 8 MFMA -> gate ->
//   i-reduce -> in-register LN -> xh row. MFMA2 projects at the end.
// Frag maps (verified r2): A row=l&15,k=(l>>4)*8+t; B col=l&15,k=(l>>4)*8+t;
//                          C col=l&15, row=4*(l>>4)+reg.
// ---------------------------------------------------------------------------
__global__ __launch_bounds__(64) void fused_main_kernel(
    const float* __restrict__ trans, const int* __restrict__ eidx,
    const float* __restrict__ g1, const float* __restrict__ g2,
    const float* __restrict__ ef, const float* __restrict__ b_edge,
    const float* __restrict__ b_db, const float* __restrict__ bias2,
    const unsigned short* __restrict__ wdbF,
    const unsigned short* __restrict__ wedF,
    const unsigned short* __restrict__ woF,
    float* __restrict__ out)
{
  __shared__ float t_l[KNB][4];
  __shared__ float g2l[KNB][68];
  __shared__ unsigned short xh[KNB][72];

  const int n = blockIdx.x;
  const int l = threadIdx.x;           // 0..63
  const int q = l >> 4, c = l & 15;
  const int base = n*KNB;

  // ---- index + gather traffic (all front-loaded, no sync needed) --------
  const int e_c = eidx[base + c];            // node of edge i=c (t_i)
  const int e_g = eidx[base + (l >> 2)];     // g2-staging row
  int e_q[4];
  #pragma unroll
  for (int r = 0; r < 4; ++r) e_q[r] = eidx[base + 4*q + r];

  const float tc0 = trans[e_c*3+0], tc1 = trans[e_c*3+1], tc2 = trans[e_c*3+2];
  if (l < 16) { t_l[l][0] = tc0; t_l[l][1] = tc1; t_l[l][2] = tc2; }

  { // stage g2 rows: row = l>>2, 16 cols per lane
    const int row = l >> 2, c0 = (l & 3) * 16;
    const float* src = &g2[e_g*CZ + c0];
    #pragma unroll
    for (int k = 0; k < 4; ++k)
      *(f32x4*)&g2l[row][c0 + 4*k] = *(const f32x4*)&src[4*k];
  }

  float g1v[4][4];                           // G1[i=4q+r][h=16nt+c]
  #pragma unroll
  for (int nt = 0; nt < 4; ++nt)
    #pragma unroll
    for (int r = 0; r < 4; ++r)
      g1v[nt][r] = g1[e_q[r]*CZ + 16*nt + c];

  // wdb B-frags: kept in registers for the whole mt loop (32 VGPRs)
  short8 bfr[2][4];
  #pragma unroll
  for (int s = 0; s < 2; ++s)
    #pragma unroll
    for (int nt = 0; nt < 4; ++nt)
      bfr[s][nt] = *(const short8*)&wdbF[((s*4 + nt)*64 + l)*8];

  // ---- MFMA0: kf = ef @ w_edge + b_edge (C-frag = gate layout) ----------
  short8 afe[2];
  #pragma unroll
  for (int s = 0; s < 2; ++s) {
    const float* src = &ef[(base + c)*CZ + 32*s + 8*q];
    const f32x4 x0 = *(const f32x4*)src;
    const f32x4 x1 = *(const f32x4*)(src + 4);
    uint4v u;
    u[0] = pk2(x0[0], x0[1]);
    u[1] = pk2(x0[2], x0[3]);
    u[2] = pk2(x1[0], x1[1]);
    u[3] = pk2(x1[2], x1[3]);
    short8 v;
    __builtin_memcpy(&v, &u, 16);
    afe[s] = v;
  }
  f32x4 accK[4];                             // kf[i=4q+r][h=16nt+c]
  #pragma unroll
  for (int nt = 0; nt < 4; ++nt) {
    const float be = b_edge[16*nt + c];
    accK[nt] = (f32x4){be, be, be, be};
  }
  #pragma unroll
  for (int s = 0; s < 2; ++s)
    #pragma unroll
    for (int nt = 0; nt < 4; ++nt) {
      const short8 wed = *(const short8*)&wedF[(s*256 + nt*64 + l)*8];
      accK[nt] = __builtin_amdgcn_mfma_f32_16x16x32_bf16(afe[s], wed, accK[nt], 0, 0, 0);
    }

  float bdb[4];
  #pragma unroll
  for (int nt = 0; nt < 4; ++nt) bdb[nt] = b_db[16*nt + c];

  // ---- stream the 16 j-tiles --------------------------------------------
  const float STEP = 1.2201878439258035f;    // (20/63)*3.2*sqrt(log2e)
  const float qoff = (float)(8*q) * STEP;

  #pragma unroll 4
  for (int mt = 0; mt < KNB; ++mt) {
    const float tj0 = t_l[mt][0], tj1 = t_l[mt][1], tj2 = t_l[mt][2];
    const float dx = tc0 - tj0 + 1e-8f;
    const float dy = tc1 - tj1 + 1e-8f;
    const float dz = tc2 - tj2 + 1e-8f;
    const float dsc = sqrtf(fmaf(dx,dx, fmaf(dy,dy, dz*dz))) * 3.8435917081166394f;

    // rbf A-frag: row i=c, k = 32s+8q+t
    short8 af[2];
    #pragma unroll
    for (int s = 0; s < 2; ++s) {
      const float bse = dsc - qoff - (float)(32*s) * STEP;
      uint4v u;
      #pragma unroll
      for (int t = 0; t < 4; ++t) {
        const float ua = fmaf(-STEP, (float)(2*t),   bse);
        const float ub = fmaf(-STEP, (float)(2*t+1), bse);
        u[t] = pk2(fexp2(-ua*ua), fexp2(-ub*ub));
      }
      short8 v;
      __builtin_memcpy(&v, &u, 16);
      af[s] = v;
    }

    // DB tile for j=mt (C-init = b_db)
    f32x4 accD[4];
    #pragma unroll
    for (int nt = 0; nt < 4; ++nt)
      accD[nt] = (f32x4){bdb[nt], bdb[nt], bdb[nt], bdb[nt]};
    #pragma unroll
    for (int s = 0; s < 2; ++s)
      #pragma unroll
      for (int nt = 0; nt < 4; ++nt)
        accD[nt] = __builtin_amdgcn_mfma_f32_16x16x32_bf16(af[s], bfr[s][nt], accD[nt], 0, 0, 0);

    // gate * DB * kf, reduce over i (4 in-lane + q-shuffles)
    float v[4];
    #pragma unroll
    for (int nt = 0; nt < 4; ++nt) {
      const float g2vm = g2l[mt][16*nt + c];
      float ss = 0.f;
      #pragma unroll
      for (int r = 0; r < 4; ++r) {
        const float gate = __builtin_amdgcn_rcpf(1.0f + fexp2(-(g1v[nt][r] + g2vm)));
        ss = fmaf(gate * accD[nt][r], accK[nt][r], ss);
      }
      ss += __shfl_xor(ss, 16);
      ss += __shfl_xor(ss, 32);
      v[nt] = ss;
    }

    // in-register LayerNorm of row j=mt (values spread over c; dup over q)
    float s1 = (v[0] + v[1]) + (v[2] + v[3]);
    float s2 = fmaf(v[0],v[0], fmaf(v[1],v[1], fmaf(v[2],v[2], v[3]*v[3])));
    #pragma unroll
    for (int mk = 1; mk <= 8; mk <<= 1) {
      s1 += __shfl_xor(s1, mk);
      s2 += __shfl_xor(s2, mk);
    }
    const float mean = s1 * 0.015625f;
    const float var  = fmaf(s2, 0.015625f, -mean*mean);
    const float rstd = rsqrtf(var + 1e-5f);
    if (q == 0) {
      #pragma unroll
      for (int nt = 0; nt < 4; ++nt)
        xh[mt][16*nt + c] = bfc((v[nt] - mean) * rstd);
    }
  }

  // ---- MFMA2: out = xhat @ (ln_g*w_out) + bias2 -------------------------
  f32x4 acc2[4] = {};
  #pragma unroll
  for (int s = 0; s < 2; ++s) {
    const short8 a2f = *(const short8*)&xh[c][32*s + 8*q];
    #pragma unroll
    for (int nt2 = 0; nt2 < 4; ++nt2) {
      const short8 wb = *(const short8*)&woF[(s*256 + nt2*64 + l)*8];
      acc2[nt2] = __builtin_amdgcn_mfma_f32_16x16x32_bf16(a2f, wb, acc2[nt2], 0, 0, 0);
    }
  }
  #pragma unroll
  for (int nt2 = 0; nt2 < 4; ++nt2) {
    const float bo = bias2[16*nt2 + c];
    #pragma unroll
    for (int r = 0; r < 4; ++r)
      out[(base + 4*q + r)*CZ + 16*nt2 + c] = acc2[nt2][r] + bo;
  }
}

extern "C" void kernel_launch(void* const* d_in, const int* in_sizes, int n_in,
                              void* d_out, int out_size, void* d_ws, size_t ws_size,
                              hipStream_t stream)
{
  const float* nf     = (const float*)d_in[0];
  const float* trans  = (const float*)d_in[1];
  const float* ef     = (const float*)d_in[2];
  const int*   eidx   = (const int*)d_in[3];
  const float* w_gate = (const float*)d_in[4];
  const float* b_gate = (const float*)d_in[5];
  const float* w_db   = (const float*)d_in[6];
  const float* b_db   = (const float*)d_in[7];
  const float* w_edge = (const float*)d_in[8];
  const float* b_edge = (const float*)d_in[9];
  const float* ln_g   = (const float*)d_in[10];
  const float* ln_b   = (const float*)d_in[11];
  const float* w_out  = (const float*)d_in[12];
  const float* b_out  = (const float*)d_in[13];
  float* out = (float*)d_out;

  float* g1    = (float*)d_ws;                            // [2000][64] f32
  float* g2    = g1 + NND*CZ;                             // [2000][64] f32
  float* bias2 = g2 + NND*CZ;                             // [64] f32
  unsigned short* wdbF = (unsigned short*)(bias2 + CZ);   // 4096 bf16
  unsigned short* wedF = wdbF + 4096;                     // 4096 bf16
  unsigned short* woF  = wedF + 4096;                     // 4096 bf16

  precompute_kernel<<<NND/4 + 1, 256, 0, stream>>>(
      nf, w_gate, b_gate, ln_b, w_out, b_out, w_db, w_edge, ln_g,
      g1, g2, bias2, wdbF, wedF, woF);
  fused_main_kernel<<<NND, 64, 0, stream>>>(
      trans, eidx, g1, g2, ef, b_edge, b_db, bias2,
      wdbF, wedF, woF, out);
}